// Round 4
// baseline (84.777 us; speedup 1.0000x reference)
//
#include <hip/hip_runtime.h>
#include <math.h>

#define NB 16
#define NA 5
#define NH 96
#define NW 96
#define TT 50
#define HW (NH*NW)        // 9216
#define APB (NA*HW)       // 46080 cells per batch
#define CPT 2             // R15 occupancy probe: 2 cells/thread, 2x blocks
#define CPB (256*CPT)     // 512 cells per block
#define NBLK (APB/CPB)    // 90 blocks in x
#define NPART (NBLK*NB)   // 1440 partials

__device__ __constant__ float c_aw[NA] = {1.3221f, 3.19275f, 5.05587f, 9.47112f, 11.2364f};
__device__ __constant__ float c_ah[NA] = {1.73145f, 4.00944f, 8.09892f, 4.84053f, 10.0071f};

__device__ __forceinline__ float sigmoidf(float x) { return 1.0f / (1.0f + __expf(-x)); }

// R9 structure. Wave 0 does: s_map init + GT prep + branchless shuffle
// winner scan + scatter, while other waves' hoisted channel loads stream.
// DO NOT restructure the prologue (R11/R8 regressed >15 µs).
//
// R12: 1.6x pre-scale, 9-op hot loop: -1.2 µs (noise). NOT VALU-count-bound.
// R13: launch_bounds(256,3): neutral. NOT residency-cap-bound.
// R14: atomic -> ws partials + reduce dispatch: neutral. NOT atomic-bound.
// Main kernel pinned at ~38-39 µs vs ~10 µs issue model.
//
// R15 (this probe): the last untested axis — TLP. 11.2 waves/CU (2.81
// blocks x 4 waves) may simply be too thin to hide LDS-return latency +
// short dependent VALU chains. CPT 4->2: same total VALU work, 1440 blocks,
// launch_bounds(256,6) pins 6 blocks/CU (VGPR cap 85) -> 1536 resident
// capacity >= 1440 -> single round at 22.5 waves/CU = 2x TLP. Unroll 10->5
// to keep ra-prefetch depth inside the 85-reg cap.
// Pre-committed: win => stall-bound confirmed; neutral => issue/clock/
// harness floor, restore single-kernel form and close.
__global__ __launch_bounds__(256, 6)
void yolo_loss_fused(const float* __restrict__ outp,
                     const float* __restrict__ target,
                     float* __restrict__ part) {
    __shared__ float s_hot[TT*8];    // 1.6*gxl, 1.6*gxr, gyl, gyr, g06n(-0.6*garea | -1e30), 0,0,0
    __shared__ float s_cold[TT*8];   // garea,tx,ty,tw,th,tcls,lr,0
    __shared__ int   s_map[CPB];     // local cell -> winning GT index (-1)
    __shared__ float s_sum[4];

    int b   = blockIdx.y;
    int tid = threadIdx.x;
    int base_cell = blockIdx.x * CPB;

    int cell0 = base_cell + tid*CPT;
    int a   = cell0 / HW;                  // 512 | 9216: blocks never straddle an anchor
    int rem = cell0 - a*HW;
    int j   = rem / NW;
    int i0  = rem - j*NW;                  // 2 | 96: pairs never straddle a row

    // ---- hoisted global loads (barrier-independent: outp is read-only) ----
    const float* base = outp + (size_t)((b*NA + a)*8)*HW + rem;
    float2 v0 = *(const float2*)(base + 0*HW);
    float2 v1 = *(const float2*)(base + 1*HW);
    float2 v2 = *(const float2*)(base + 2*HW);
    float2 v3 = *(const float2*)(base + 3*HW);
    float2 v4 = *(const float2*)(base + 4*HW);

    // ---- prologue: wave 0 only, wave-internal LDS coherence, one barrier ----
    if (tid < 64) {
        int4 neg = {-1, -1, -1, -1};
        #pragma unroll
        for (int k = 0; k < CPB/256; ++k)           // 128 int4s, 2 per lane
            ((int4*)s_map)[tid + k*64] = neg;

        int t = tid;
        float xraw = (t < TT) ? target[(b*TT + t)*6 + 1] : 1.0f;
        unsigned long long m = __ballot(xraw != 0.0f);

        int cell = -1;
        if (t < TT) {
            int valid = (((~m) & ((2ull << t) - 1ull)) == 0ull) ? 1 : 0;
            const float* tg = target + (b*TT + t)*6;
            float tcls = tg[0];
            float gx = tg[1]*NW, gy = tg[2]*NH, gw = tg[3]*NW, gh = tg[4]*NH;
            float lr = tg[5];
            int best = 0; float bi = -1.0f;
            for (int a2 = 0; a2 < NA; ++a2) {
                float inter = fminf(gw, c_aw[a2]) * fminf(gh, c_ah[a2]);
                float iou = inter / (gw*gh + c_aw[a2]*c_ah[a2] - inter);
                if (iou > bi) { bi = iou; best = a2; }
            }
            int gi = (int)gx, gj = (int)gy;
            cell = valid ? (best*HW + gj*NW + gi) : -1;
            float* rh = &s_hot[t*8];
            if (valid) {
                rh[0] = 1.6f*(gx - 0.5f*gw); rh[1] = 1.6f*(gx + 0.5f*gw);
                rh[2] = gy - 0.5f*gh;        rh[3] = gy + 0.5f*gh;
                rh[4] = -0.6f*gw*gh;
            } else {
                rh[0] = 0.0f; rh[1] = 0.0f; rh[2] = 0.0f; rh[3] = 0.0f;
                rh[4] = -1e30f;
            }
            rh[5] = 0.0f; rh[6] = 0.0f; rh[7] = 0.0f;
            float* rc = &s_cold[t*8];
            rc[0] = gw*gh;
            rc[1] = gx - (float)gi;  rc[2] = gy - (float)gj;
            rc[3] = logf(gw / c_aw[best]); rc[4] = logf(gh / c_ah[best]);
            rc[5] = tcls; rc[6] = lr; rc[7] = 0.0f;
        }
        // winner = no later valid t maps to this cell (scan scatter = last-write-wins)
        unsigned win = (cell >= 0) ? 1u : 0u;
        #pragma unroll
        for (int u = 1; u < TT; ++u) {
            int cu = __shfl_down(cell, u, 64);
            win &= ((t + u >= TT) || (cu != cell)) ? 1u : 0u;
        }
        if (win) {
            int local = cell - base_cell;
            if ((unsigned)local < CPB) s_map[local] = t;
        }
    }
    __syncthreads();

    int2  mp  = *(const int2*)(&s_map[tid*CPT]);   // 8B/lane LDS
    float o0[CPT] = {v0.x, v0.y};
    float o1[CPT] = {v1.x, v1.y};
    float o2[CPT] = {v2.x, v2.y};
    float o3[CPT] = {v3.x, v3.y};
    float o4[CPT] = {v4.x, v4.y};
    int   mc[CPT] = {mp.x, mp.y};

    float aw = c_aw[a], ah = c_ah[a];
    // x-side boxes carried PRE-SCALED by 1.6 (see R12 note above).
    float pxl16[CPT], pxr16[CPT], pyl[CPT], pyr[CPT], parea[CPT], maxv[CPT];
    #pragma unroll
    for (int c = 0; c < CPT; ++c) {
        float sx = sigmoidf(o0[c]), sy = sigmoidf(o1[c]);
        float px = sx + (float)(i0 + c);
        float py = sy + (float)j;
        float pw = __expf(o2[c]) * aw;
        float ph = __expf(o3[c]) * ah;
        float px16 = 1.6f*px;
        pxl16[c] = fmaf(-0.8f, pw, px16); pxr16[c] = fmaf(0.8f, pw, px16);
        pyl[c] = py - 0.5f*ph; pyr[c] = py + 0.5f*ph;
        parea[c] = pw*ph;
        maxv[c] = -1e30f;
    }

    // GT loop: LDS broadcast reads at immediate offsets, no address VALU.
    // One-clamp trick: score = max(cw16,0)*ch + g06n (safe: see R12 note).
    // 9 VALU ops per (cell,GT).
    #pragma unroll 5
    for (int t = 0; t < TT; ++t) {
        float4 ra  = *(const float4*)(&s_hot[t*8]);   // ds_read_b128
        float g06n = s_hot[t*8 + 4];                  // ds_read_b32
        #pragma unroll
        for (int c = 0; c < CPT; ++c) {
            float cw = fminf(pxr16[c], ra.y) - fmaxf(pxl16[c], ra.x);
            float ch = fminf(pyr[c], ra.w) - fmaxf(pyl[c], ra.z);
            maxv[c] = fmaxf(maxv[c], fmaf(fmaxf(cw, 0.0f), ch, g06n));
        }
    }

    float acc = 0.0f;
    #pragma unroll
    for (int c = 0; c < CPT; ++c) {
        float conf = sigmoidf(o4[c]);
        int tw_idx = mc[c];
        if (tw_idx >= 0) {                         // rare (~800 / 737280 cells)
            const float* cr = &s_cold[tw_idx*8];
            float garea = cr[0], tx = cr[1], ty = cr[2];
            float tw = cr[3], th = cr[4], tcls = cr[5], lr = cr[6];
            const float* rh = &s_hot[tw_idx*8];
            // true cw = 0.625 * scaled cw (0.625 = 1/1.6 exact).
            float cw = 0.625f*(fminf(pxr16[c], rh[1]) - fmaxf(pxl16[c], rh[0]));
            float ch = fminf(pyr[c], rh[3]) - fmaxf(pyl[c], rh[2]);
            float carea = fmaxf(cw, 0.0f) * fmaxf(ch, 0.0f);   // exact form here
            float tconf = carea / (parea[c] + garea - carea);
            float dc = conf - tconf;
            float term = 2.5f*dc*dc;               // 0.5 * OBJECT_SCALE
            float sx = sigmoidf(o0[c]), sy = sigmoidf(o1[c]);
            float dx = sx - tx, dy = sy - ty, dw = o2[c] - tw, dh = o3[c] - th;
            term += 0.5f*(dx*dx + dy*dy + dw*dw + dh*dh);
            float o5 = base[5*HW + c], o6 = base[6*HW + c], o7 = base[7*HW + c];
            float mm  = fmaxf(o5, o6);
            float lse = mm + __logf(__expf(o5 - mm) + __expf(o6 - mm));
            term += lse - ((tcls != 0.0f) ? o6 : o5);   // 2-class CE
            float dl = sigmoidf(o7) - lr;
            term += 0.25f*dl*dl;                   // 0.5 * mse_half(conf_lr)
            acc += term;
        } else {
            acc += (maxv[c] > 0.6f*parea[c]) ? 0.0f : 0.5f*conf*conf;
        }
    }

    // wave64 + block reduction, one plain store per block (R14: no atomics)
    for (int off = 32; off > 0; off >>= 1) acc += __shfl_down(acc, off, 64);
    int lane = tid & 63, wid = tid >> 6;
    if (lane == 0) s_sum[wid] = acc;
    __syncthreads();
    if (tid == 0) {
        float s = (s_sum[0] + s_sum[1]) + (s_sum[2] + s_sum[3]);
        part[b*NBLK + blockIdx.x] = s;     // distinct address per block
    }
}

// Tiny second dispatch: sum 1440 partials, overwrite d_out.
__global__ __launch_bounds__(256)
void yolo_reduce(const float* __restrict__ part, float* __restrict__ loss) {
    __shared__ float s_sum[4];
    int tid = threadIdx.x;
    float acc = part[tid] + part[tid + 256] + part[tid + 512]
              + part[tid + 768] + part[tid + 1024];        // 1280 <= NPART
    if (tid < NPART - 1280) acc += part[tid + 1280];       // tail 160
    for (int off = 32; off > 0; off >>= 1) acc += __shfl_down(acc, off, 64);
    int lane = tid & 63, wid = tid >> 6;
    if (lane == 0) s_sum[wid] = acc;
    __syncthreads();
    if (tid == 0)
        loss[0] = ((s_sum[0] + s_sum[1]) + (s_sum[2] + s_sum[3])) * (1.0f/NB);
}

extern "C" void kernel_launch(void* const* d_in, const int* in_sizes, int n_in,
                              void* d_out, int out_size, void* d_ws, size_t ws_size,
                              hipStream_t stream) {
    const float* output = (const float*)d_in[0];
    const float* target = (const float*)d_in[1];
    float* part = (float*)d_ws;            // 1440 floats of the ws
    float* out  = (float*)d_out;

    dim3 grid(NBLK, NB);                   // 90 x 16 = 1440 blocks
    hipLaunchKernelGGL(yolo_loss_fused, grid, dim3(256), 0, stream,
                       output, target, part);
    hipLaunchKernelGGL(yolo_reduce, dim3(1), dim3(256), 0, stream,
                       part, out);
}